// Round 4
// baseline (471.798 us; speedup 1.0000x reference)
//
#include <hip/hip_runtime.h>
#include <cstdint>
#include <cstddef>

typedef _Float16 f16;
typedef _Float16 f16x4 __attribute__((ext_vector_type(4)));
typedef _Float16 f16x8 __attribute__((ext_vector_type(8)));
typedef float f32x4 __attribute__((ext_vector_type(4)));

#define DEVI __device__ __forceinline__

DEVI void gload_lds16(const void* g, void* l) {
  __builtin_amdgcn_global_load_lds(
      (const __attribute__((address_space(1))) void*)g,
      (__attribute__((address_space(3))) void*)l, 16, 0, 0);
}

DEVI float fexp2(float x) { return __builtin_amdgcn_exp2f(x); }

// ---------------- f32 -> f16 convert, 8 elems/thread ----------------
__global__ void k_cvt(const float* __restrict__ in, f16* __restrict__ out, int n) {
  int i = (blockIdx.x * 256 + threadIdx.x) * 8;
  if (i >= n) return;
  const float4* p = reinterpret_cast<const float4*>(in + i);
  float4 a = p[0], b = p[1];
  f16x8 o;
  o[0] = (f16)a.x; o[1] = (f16)a.y; o[2] = (f16)a.z; o[3] = (f16)a.w;
  o[4] = (f16)b.x; o[5] = (f16)b.y; o[6] = (f16)b.z; o[7] = (f16)b.w;
  *reinterpret_cast<f16x8*>(out + i) = o;
}

// ---------------- GEMM: C[M,N] = A[M,K] * B[N,K]^T ----------------
template<int OUTF32>
__global__ __launch_bounds__(256) void k_gemm(
    const f16* __restrict__ A,
    const f16* __restrict__ B0, const f16* __restrict__ B1, const f16* __restrict__ B2,
    void* __restrict__ C0, void* __restrict__ C1, void* __restrict__ C2) {
  constexpr int K = 1024, N = 1024;
  __shared__ f16 As[128 * 64];
  __shared__ f16 Bs[128 * 64];
  const f16* B = (blockIdx.z == 0) ? B0 : ((blockIdx.z == 1) ? B1 : B2);
  void* C = (blockIdx.z == 0) ? C0 : ((blockIdx.z == 1) ? C1 : C2);
  const int tid = threadIdx.x;
  const int lane = tid & 63;
  const int wave = tid >> 6;
  const int wr = wave >> 1, wc = wave & 1;
  const int l15 = lane & 15, l4 = lane >> 4;
  const int m0 = blockIdx.y * 128, n0 = blockIdx.x * 128;
  const int srow = tid >> 3, su = tid & 7;

  f32x4 acc[4][4] = {};

  for (int kt = 0; kt < K; kt += 64) {
    __syncthreads();
#pragma unroll
    for (int q = 0; q < 4; ++q) {
      int r = q * 32 + srow;
      int ce = (su ^ (r & 7)) * 8;
      gload_lds16(A + (size_t)(m0 + r) * K + kt + ce,
                  (char*)As + (q * 256 + (tid & 192)) * 16);
    }
#pragma unroll
    for (int q = 0; q < 4; ++q) {
      int r = q * 32 + srow;
      int ce = (su ^ (r & 7)) * 8;
      gload_lds16(B + (size_t)(n0 + r) * K + kt + ce,
                  (char*)Bs + (q * 256 + (tid & 192)) * 16);
    }
    __syncthreads();
#pragma unroll
    for (int kk = 0; kk < 2; ++kk) {
      f16x8 af[4], bf[4];
#pragma unroll
      for (int mi = 0; mi < 4; ++mi) {
        int r = wr * 64 + mi * 16 + l15;
        int u = (kk * 4 + l4) ^ (r & 7);
        af[mi] = *reinterpret_cast<const f16x8*>((const char*)As + r * 128 + u * 16);
      }
#pragma unroll
      for (int ni = 0; ni < 4; ++ni) {
        int r = wc * 64 + ni * 16 + l15;
        int u = (kk * 4 + l4) ^ (r & 7);
        bf[ni] = *reinterpret_cast<const f16x8*>((const char*)Bs + r * 128 + u * 16);
      }
#pragma unroll
      for (int mi = 0; mi < 4; ++mi)
#pragma unroll
        for (int ni = 0; ni < 4; ++ni)
          acc[mi][ni] = __builtin_amdgcn_mfma_f32_16x16x32_f16(af[mi], bf[ni], acc[mi][ni], 0, 0, 0);
    }
  }
#pragma unroll
  for (int mi = 0; mi < 4; ++mi)
#pragma unroll
    for (int ni = 0; ni < 4; ++ni)
#pragma unroll
      for (int r = 0; r < 4; ++r) {
        int row = m0 + wr * 64 + mi * 16 + l4 * 4 + r;
        int col = n0 + wc * 64 + ni * 16 + l15;
        if (OUTF32)
          ((float*)C)[(size_t)row * N + col] = acc[mi][ni][r];
        else
          ((f16*)C)[(size_t)row * N + col] = (f16)acc[mi][ni][r];
      }
}

// ---------------- RoPE in-place on Q and K ----------------
__global__ void k_rope(f16* __restrict__ Q, f16* __restrict__ Kk,
                       const int* __restrict__ pE, const int* __restrict__ pSkip) {
  int idx = blockIdx.x * 256 + threadIdx.x;
  int t = idx & 31;
  int h = (idx >> 5) & 15;
  int s = (idx >> 9) & 2047;
  int b = idx >> 20;
  int E = *pE, skip = *pSkip;
  int p;
  if (skip) { if (s < E) return; p = s - E; } else { p = s; }
  float inv_freq = powf(10000.0f, -(float)t / 32.0f);
  float ang = (float)p * inv_freq;
  float sn, cs;
  sincosf(ang, &sn, &cs);
  size_t base = ((size_t)((b * 2048 + s) * 16 + h)) * 64 + 2 * t;
  union UU { unsigned u; f16 h2[2]; };
  UU qv; qv.u = *reinterpret_cast<const unsigned*>(Q + base);
  float q0 = (float)qv.h2[0], q1 = (float)qv.h2[1];
  qv.h2[0] = (f16)(q0 * cs - q1 * sn);
  qv.h2[1] = (f16)(q1 * cs + q0 * sn);
  *reinterpret_cast<unsigned*>(Q + base) = qv.u;
  UU kv; kv.u = *reinterpret_cast<const unsigned*>(Kk + base);
  float k0 = (float)kv.h2[0], k1 = (float)kv.h2[1];
  kv.h2[0] = (f16)(k0 * cs - k1 * sn);
  kv.h2[1] = (f16)(k1 * cs + k0 * sn);
  *reinterpret_cast<unsigned*>(Kk + base) = kv.u;
}

// ---------------- V transpose: (b,s,h*64+d) -> (bh, d, s) ----------------
__global__ __launch_bounds__(256) void k_vtrans(const f16* __restrict__ Vf, f16* __restrict__ Vt) {
  __shared__ f16 tile[64 * 64];
  const int sb = blockIdx.x, bh = blockIdx.y;
  const int b = bh >> 4, h = bh & 15;
  const int tid = threadIdx.x;
#pragma unroll
  for (int it = 0; it < 2; ++it) {
    int i = it * 32 + (tid >> 3);
    int u = tid & 7;
    f16x8 v = *reinterpret_cast<const f16x8*>(
        Vf + ((size_t)(b * 2048 + sb * 64 + i)) * 1024 + h * 64 + u * 8);
    int us = u ^ (i & 7);
    *reinterpret_cast<f16x8*>(&tile[i * 64 + us * 8]) = v;
  }
  __syncthreads();
  const int j = tid >> 2;
  const int c0 = (tid & 3) * 16;
  f16 vals[16];
#pragma unroll
  for (int k = 0; k < 16; ++k) {
    int i = c0 + k;
    vals[k] = tile[i * 64 + (((j >> 3) ^ (i & 7)) << 3) + (j & 7)];
  }
  f16x8 o0, o1;
#pragma unroll
  for (int k = 0; k < 8; ++k) { o0[k] = vals[k]; o1[k] = vals[8 + k]; }
  f16* dst = Vt + (size_t)bh * 131072 + (size_t)j * 2048 + sb * 64 + c0;
  *reinterpret_cast<f16x8*>(dst) = o0;
  *reinterpret_cast<f16x8*>(dst + 8) = o1;
}

// ---------------- flash attention (swapped QK^T, in-lane softmax) ----------
// mfma(K,Q) -> S^T: lane holds 16 scores of ONE q-row (q=l15, kv=l4*4+r+16jt).
// Softmax = in-lane tree + 2 shfl_xor (combine 4 l4-replicas); running sum is
// per-lane partial (reduced once at end); alpha moved to acc row-layout via 4
// independent bpermutes. P -> wave-private LDS as 4x8B swizzled stores, read
// back as 8x b64 A-fragments. PV + epilogue unchanged.
__global__ __launch_bounds__(256) void k_attn(
    const f16* __restrict__ Q, const f16* __restrict__ Kg, const f16* __restrict__ Vt,
    const int* __restrict__ amask, const int* __restrict__ pE,
    f16* __restrict__ AO) {
  __shared__ f16 P_lds[4][2][16 * 64];
  const int lid = (blockIdx.x & 7) * 256 + (blockIdx.x >> 3);  // XCD swizzle (2048%8==0)
  const int bh = lid >> 5;
  const int qb = 31 - (lid & 31);                              // heavy blocks first
  const int b = bh >> 4, h = bh & 15;
  const int tid = threadIdx.x;
  const int wave = tid >> 6, lane = tid & 63;
  const int l15 = lane & 15, l4 = lane >> 4;
  const int E = *pE;
  const int qrow0 = qb * 64 + wave * 16;
  const int irow = qrow0 + l15;   // this lane's q-row in softmax (S^T) layout
  constexpr float SCALE = 0.125f * 1.44269504088896f;  // dh^-0.5 * log2(e)

  f16x8 qf0, qf1;
  {
    const f16* qp = Q + ((size_t)(b * 2048 + qrow0 + l15)) * 1024 + h * 64;
    qf0 = *reinterpret_cast<const f16x8*>(qp + l4 * 8);
    qf1 = *reinterpret_cast<const f16x8*>(qp + 32 + l4 * 8);
  }
  f32x4 acc[4] = {};
  float mq = -1e30f;   // running row max (lane layout, q=l15)
  float lq = 0.f;      // running PARTIAL row sum (this lane's kv columns)

  int nkv = qb + 1;
  int ekv = (E + 63) >> 6;
  if (ekv > nkv) nkv = ekv;
  if (nkv > 32) nkv = 32;

  auto LOADK = [&](int jb, f16x8* k0, f16x8* k1) {
#pragma unroll
    for (int jt = 0; jt < 4; ++jt) {
      const f16* kp = Kg + ((size_t)(b * 2048 + jb * 64 + jt * 16 + l15)) * 1024 + h * 64;
      k0[jt] = *reinterpret_cast<const f16x8*>(kp + l4 * 8);
      k1[jt] = *reinterpret_cast<const f16x8*>(kp + 32 + l4 * 8);
    }
  };

  auto BODY = [&](int jb, const f16x8* kc0, const f16x8* kc1,
                  f16x8* kn0, f16x8* kn1, int pb) {
    // QK^T swapped: st[jt][r] = S[kv = jb*64+jt*16+l4*4+r][q = irow]
    f32x4 st[4];
#pragma unroll
    for (int jt = 0; jt < 4; ++jt) {
      f32x4 s = {};
      s = __builtin_amdgcn_mfma_f32_16x16x32_f16(kc0[jt], qf0, s, 0, 0, 0);
      s = __builtin_amdgcn_mfma_f32_16x16x32_f16(kc1[jt], qf1, s, 0, 0, 0);
      st[jt] = s;
    }
    // issue V + amask loads now (consumed after softmax -> latency hidden)
    f16x8 vb0[4], vb1[4];
#pragma unroll
    for (int dt = 0; dt < 4; ++dt) {
      const f16* vp = Vt + (size_t)bh * 131072 + (size_t)(dt * 16 + l15) * 2048 + jb * 64;
      vb0[dt] = *reinterpret_cast<const f16x8*>(vp + l4 * 8);
      vb1[dt] = *reinterpret_cast<const f16x8*>(vp + 32 + l4 * 8);
    }
    int4 am[4];
#pragma unroll
    for (int jt = 0; jt < 4; ++jt)
      am[jt] = *reinterpret_cast<const int4*>(amask + b * 2048 + jb * 64 + jt * 16 + l4 * 4);
    // prefetch next K tile into the other register set
    int jn = (jb + 1 < nkv) ? jb + 1 : jb;
    LOADK(jn, kn0, kn1);
    // mask + scale (log2 domain); kv index is per-(jt,r,l4), q is l15
#pragma unroll
    for (int jt = 0; jt < 4; ++jt) {
      const int* amv = reinterpret_cast<const int*>(&am[jt]);
#pragma unroll
      for (int r = 0; r < 4; ++r) {
        int jcol = jb * 64 + jt * 16 + l4 * 4 + r;
        bool vis = (amv[r] != 0) && ((jcol <= irow) || (jcol < E));
        st[jt][r] = vis ? st[jt][r] * SCALE : -1e30f;
      }
    }
    // in-lane max tree (15 fmax, depth 4) + 2 shfl to merge l4-replicas
    float t0 = fmaxf(fmaxf(st[0][0], st[0][1]), fmaxf(st[0][2], st[0][3]));
    float t1 = fmaxf(fmaxf(st[1][0], st[1][1]), fmaxf(st[1][2], st[1][3]));
    float t2 = fmaxf(fmaxf(st[2][0], st[2][1]), fmaxf(st[2][2], st[2][3]));
    float t3 = fmaxf(fmaxf(st[3][0], st[3][1]), fmaxf(st[3][2], st[3][3]));
    float mt = fmaxf(fmaxf(t0, t1), fmaxf(t2, t3));
    mt = fmaxf(mt, __shfl_xor(mt, 16, 64));
    mt = fmaxf(mt, __shfl_xor(mt, 32, 64));
    float mnew = fmaxf(mq, mt);
    float alpha = fexp2(mq - mnew);   // mq==mnew==-1e30 -> 1, harmless (lq==0)
    // p = exp2(s - mnew), per-lane partial sum; pack 4 f16 per jt -> LDS 8B
    float psum = 0.f;
#pragma unroll
    for (int jt = 0; jt < 4; ++jt) {
      f16x4 pk;
#pragma unroll
      for (int r = 0; r < 4; ++r) {
        float sv = st[jt][r];
        float p = (sv <= -1e29f) ? 0.f : fexp2(sv - mnew);
        psum += p;
        pk[r] = (f16)p;
      }
      int u = (jt * 4 + l4) ^ l15;  // unit swizzle within the q-row
      *reinterpret_cast<f16x4*>(&P_lds[wave][pb][l15 * 64 + u * 4]) = pk;
    }
    lq = lq * alpha + psum;
    mq = mnew;
    // alpha -> accumulator row layout (row = l4*4+r lives at lane l15==row)
    float ar[4];
#pragma unroll
    for (int r = 0; r < 4; ++r)
      ar[r] = __shfl(alpha, (l4 << 4) | (l4 * 4 + r), 64);
#pragma unroll
    for (int dt = 0; dt < 4; ++dt)
#pragma unroll
      for (int r = 0; r < 4; ++r) acc[dt][r] *= ar[r];
    // wave-private P roundtrip
    asm volatile("s_waitcnt lgkmcnt(0)" ::: "memory");
    __builtin_amdgcn_sched_barrier(0);
    const f16* Pw = &P_lds[wave][pb][0];
    f16x4 a00 = *reinterpret_cast<const f16x4*>(&Pw[l15 * 64 + (((l4 * 2    )) ^ l15) * 4]);
    f16x4 a01 = *reinterpret_cast<const f16x4*>(&Pw[l15 * 64 + (((l4 * 2 + 1)) ^ l15) * 4]);
    f16x4 a10 = *reinterpret_cast<const f16x4*>(&Pw[l15 * 64 + ((8 + l4 * 2    ) ^ l15) * 4]);
    f16x4 a11 = *reinterpret_cast<const f16x4*>(&Pw[l15 * 64 + ((8 + l4 * 2 + 1) ^ l15) * 4]);
    f16x8 pa0, pa1;
#pragma unroll
    for (int i = 0; i < 4; ++i) {
      pa0[i] = a00[i]; pa0[4 + i] = a01[i];
      pa1[i] = a10[i]; pa1[4 + i] = a11[i];
    }
#pragma unroll
    for (int dt = 0; dt < 4; ++dt) {
      acc[dt] = __builtin_amdgcn_mfma_f32_16x16x32_f16(pa0, vb0[dt], acc[dt], 0, 0, 0);
      acc[dt] = __builtin_amdgcn_mfma_f32_16x16x32_f16(pa1, vb1[dt], acc[dt], 0, 0, 0);
    }
  };

  f16x8 kA0[4], kA1[4], kB0[4], kB1[4];
  LOADK(0, kA0, kA1);
  int jb = 0, pb = 0;
  while (true) {
    BODY(jb, kA0, kA1, kB0, kB1, pb);
    if (++jb >= nkv) break;
    pb ^= 1;
    BODY(jb, kB0, kB1, kA0, kA1, pb);
    if (++jb >= nkv) break;
    pb ^= 1;
  }

  // final row-sum: merge l4-replica partials, then move to acc row layout
  float lf = lq;
  lf += __shfl_xor(lf, 16, 64);
  lf += __shfl_xor(lf, 32, 64);
#pragma unroll
  for (int r = 0; r < 4; ++r) {
    float lr = __shfl(lf, (l4 << 4) | (l4 * 4 + r), 64);
    float inv = 1.0f / lr;
    int row = qrow0 + l4 * 4 + r;
    f16* op = AO + ((size_t)(b * 2048 + row)) * 1024 + h * 64;
#pragma unroll
    for (int dt = 0; dt < 4; ++dt)
      op[dt * 16 + l15] = (f16)(acc[dt][r] * inv);
  }
}

// ---------------- launcher ----------------
extern "C" void kernel_launch(void* const* d_in, const int* in_sizes, int n_in,
                              void* d_out, int out_size, void* d_ws, size_t ws_size,
                              hipStream_t stream) {
  const float* x  = (const float*)d_in[0];
  const float* Wq = (const float*)d_in[1];
  const float* Wk = (const float*)d_in[2];
  const float* Wv = (const float*)d_in[3];
  const float* Wo = (const float*)d_in[4];
  const int* amask = (const int*)d_in[5];
  const int* pE    = (const int*)d_in[6];
  const int* pSkip = (const int*)d_in[7];

  char* ws = (char*)d_ws;
  f16* xb  = (f16*)(ws);
  f16* Wqb = (f16*)(ws + (16u << 20));
  f16* Wkb = (f16*)(ws + (18u << 20));
  f16* Wvb = (f16*)(ws + (20u << 20));
  f16* Wob = (f16*)(ws + (22u << 20));
  f16* Qf  = (f16*)(ws + (24u << 20));
  f16* Kf  = (f16*)(ws + (40u << 20));
  f16* Vf  = (f16*)(ws + (56u << 20));
  f16* Vt  = (f16*)(ws + (72u << 20));
  f16* AO  = xb;

  k_cvt<<<4096, 256, 0, stream>>>(x, xb, 8388608);
  k_cvt<<<512, 256, 0, stream>>>(Wq, Wqb, 1048576);
  k_cvt<<<512, 256, 0, stream>>>(Wk, Wkb, 1048576);
  k_cvt<<<512, 256, 0, stream>>>(Wv, Wvb, 1048576);
  k_cvt<<<512, 256, 0, stream>>>(Wo, Wob, 1048576);
  k_gemm<0><<<dim3(8, 64, 3), 256, 0, stream>>>(xb, Wqb, Wkb, Wvb, Qf, Kf, Vf);
  k_rope<<<16384, 256, 0, stream>>>(Qf, Kf, pE, pSkip);
  k_vtrans<<<dim3(32, 64), 256, 0, stream>>>(Vf, Vt);
  k_attn<<<2048, 256, 0, stream>>>(Qf, Kf, Vt, amask, pE, AO);
  k_gemm<1><<<dim3(8, 64, 1), 256, 0, stream>>>(AO, Wob, Wob, Wob, d_out, d_out, d_out);
}

// Round 7
// 306.094 us; speedup vs baseline: 1.5413x; 1.5413x over previous
//
#include <hip/hip_runtime.h>
#include <cstdint>
#include <cstddef>

typedef _Float16 f16;
typedef _Float16 f16x2 __attribute__((ext_vector_type(2)));
typedef _Float16 f16x4 __attribute__((ext_vector_type(4)));
typedef _Float16 f16x8 __attribute__((ext_vector_type(8)));
typedef float f32x4 __attribute__((ext_vector_type(4)));
typedef float f32x16 __attribute__((ext_vector_type(16)));

#define DEVI __device__ __forceinline__

DEVI void gload_lds16(const void* g, void* l) {
  __builtin_amdgcn_global_load_lds(
      (const __attribute__((address_space(1))) void*)g,
      (__attribute__((address_space(3))) void*)l, 16, 0, 0);
}

DEVI float fexp2(float x) { return __builtin_amdgcn_exp2f(x); }

// ---------------- f32 -> f16 convert, 8 elems/thread ----------------
__global__ void k_cvt(const float* __restrict__ in, f16* __restrict__ out, int n) {
  int i = (blockIdx.x * 256 + threadIdx.x) * 8;
  if (i >= n) return;
  const float4* p = reinterpret_cast<const float4*>(in + i);
  float4 a = p[0], b = p[1];
  f16x8 o;
  o[0] = (f16)a.x; o[1] = (f16)a.y; o[2] = (f16)a.z; o[3] = (f16)a.w;
  o[4] = (f16)b.x; o[5] = (f16)b.y; o[6] = (f16)b.z; o[7] = (f16)b.w;
  *reinterpret_cast<f16x8*>(out + i) = o;
}

// ---------------- GEMM: C[M,N] = A[M,K] * B[N,K]^T ----------------
template<int OUTF32>
__global__ __launch_bounds__(256) void k_gemm(
    const f16* __restrict__ A,
    const f16* __restrict__ B0, const f16* __restrict__ B1, const f16* __restrict__ B2,
    void* __restrict__ C0, void* __restrict__ C1, void* __restrict__ C2) {
  constexpr int K = 1024, N = 1024;
  __shared__ f16 As[128 * 64];
  __shared__ f16 Bs[128 * 64];
  const f16* B = (blockIdx.z == 0) ? B0 : ((blockIdx.z == 1) ? B1 : B2);
  void* C = (blockIdx.z == 0) ? C0 : ((blockIdx.z == 1) ? C1 : C2);
  const int tid = threadIdx.x;
  const int lane = tid & 63;
  const int wave = tid >> 6;
  const int wr = wave >> 1, wc = wave & 1;
  const int l15 = lane & 15, l4 = lane >> 4;
  const int m0 = blockIdx.y * 128, n0 = blockIdx.x * 128;
  const int srow = tid >> 3, su = tid & 7;

  f32x4 acc[4][4] = {};

  for (int kt = 0; kt < K; kt += 64) {
    __syncthreads();
#pragma unroll
    for (int q = 0; q < 4; ++q) {
      int r = q * 32 + srow;
      int ce = (su ^ (r & 7)) * 8;
      gload_lds16(A + (size_t)(m0 + r) * K + kt + ce,
                  (char*)As + (q * 256 + (tid & 192)) * 16);
    }
#pragma unroll
    for (int q = 0; q < 4; ++q) {
      int r = q * 32 + srow;
      int ce = (su ^ (r & 7)) * 8;
      gload_lds16(B + (size_t)(n0 + r) * K + kt + ce,
                  (char*)Bs + (q * 256 + (tid & 192)) * 16);
    }
    __syncthreads();
#pragma unroll
    for (int kk = 0; kk < 2; ++kk) {
      f16x8 af[4], bf[4];
#pragma unroll
      for (int mi = 0; mi < 4; ++mi) {
        int r = wr * 64 + mi * 16 + l15;
        int u = (kk * 4 + l4) ^ (r & 7);
        af[mi] = *reinterpret_cast<const f16x8*>((const char*)As + r * 128 + u * 16);
      }
#pragma unroll
      for (int ni = 0; ni < 4; ++ni) {
        int r = wc * 64 + ni * 16 + l15;
        int u = (kk * 4 + l4) ^ (r & 7);
        bf[ni] = *reinterpret_cast<const f16x8*>((const char*)Bs + r * 128 + u * 16);
      }
#pragma unroll
      for (int mi = 0; mi < 4; ++mi)
#pragma unroll
        for (int ni = 0; ni < 4; ++ni)
          acc[mi][ni] = __builtin_amdgcn_mfma_f32_16x16x32_f16(af[mi], bf[ni], acc[mi][ni], 0, 0, 0);
    }
  }
#pragma unroll
  for (int mi = 0; mi < 4; ++mi)
#pragma unroll
    for (int ni = 0; ni < 4; ++ni)
#pragma unroll
      for (int r = 0; r < 4; ++r) {
        int row = m0 + wr * 64 + mi * 16 + l4 * 4 + r;
        int col = n0 + wc * 64 + ni * 16 + l15;
        if (OUTF32)
          ((float*)C)[(size_t)row * N + col] = acc[mi][ni][r];
        else
          ((f16*)C)[(size_t)row * N + col] = (f16)acc[mi][ni][r];
      }
}

// ---------------- RoPE in-place on Q and K ----------------
__global__ void k_rope(f16* __restrict__ Q, f16* __restrict__ Kk,
                       const int* __restrict__ pE, const int* __restrict__ pSkip) {
  int idx = blockIdx.x * 256 + threadIdx.x;
  int t = idx & 31;
  int h = (idx >> 5) & 15;
  int s = (idx >> 9) & 2047;
  int b = idx >> 20;
  int E = *pE, skip = *pSkip;
  int p;
  if (skip) { if (s < E) return; p = s - E; } else { p = s; }
  float inv_freq = powf(10000.0f, -(float)t / 32.0f);
  float ang = (float)p * inv_freq;
  float sn, cs;
  sincosf(ang, &sn, &cs);
  size_t base = ((size_t)((b * 2048 + s) * 16 + h)) * 64 + 2 * t;
  union UU { unsigned u; f16 h2[2]; };
  UU qv; qv.u = *reinterpret_cast<const unsigned*>(Q + base);
  float q0 = (float)qv.h2[0], q1 = (float)qv.h2[1];
  qv.h2[0] = (f16)(q0 * cs - q1 * sn);
  qv.h2[1] = (f16)(q1 * cs + q0 * sn);
  *reinterpret_cast<unsigned*>(Q + base) = qv.u;
  UU kv; kv.u = *reinterpret_cast<const unsigned*>(Kk + base);
  float k0 = (float)kv.h2[0], k1 = (float)kv.h2[1];
  kv.h2[0] = (f16)(k0 * cs - k1 * sn);
  kv.h2[1] = (f16)(k1 * cs + k0 * sn);
  *reinterpret_cast<unsigned*>(Kk + base) = kv.u;
}

// ---------------- V transpose: (b,s,h*64+d) -> (bh, d, s) ----------------
__global__ __launch_bounds__(256) void k_vtrans(const f16* __restrict__ Vf, f16* __restrict__ Vt) {
  __shared__ f16 tile[64 * 64];
  const int sb = blockIdx.x, bh = blockIdx.y;
  const int b = bh >> 4, h = bh & 15;
  const int tid = threadIdx.x;
#pragma unroll
  for (int it = 0; it < 2; ++it) {
    int i = it * 32 + (tid >> 3);
    int u = tid & 7;
    f16x8 v = *reinterpret_cast<const f16x8*>(
        Vf + ((size_t)(b * 2048 + sb * 64 + i)) * 1024 + h * 64 + u * 8);
    int us = u ^ (i & 7);
    *reinterpret_cast<f16x8*>(&tile[i * 64 + us * 8]) = v;
  }
  __syncthreads();
  const int j = tid >> 2;
  const int c0 = (tid & 3) * 16;
  f16 vals[16];
#pragma unroll
  for (int k = 0; k < 16; ++k) {
    int i = c0 + k;
    vals[k] = tile[i * 64 + (((j >> 3) ^ (i & 7)) << 3) + (j & 7)];
  }
  f16x8 o0, o1;
#pragma unroll
  for (int k = 0; k < 8; ++k) { o0[k] = vals[k]; o1[k] = vals[8 + k]; }
  f16* dst = Vt + (size_t)bh * 131072 + (size_t)j * 2048 + sb * 64 + c0;
  *reinterpret_cast<f16x8*>(dst) = o0;
  *reinterpret_cast<f16x8*>(dst + 8) = o1;
}

// ---------------- flash attention: 32x32 swapped MFMA, in-register P ------
// 1 wave/block, 32 q-rows/wave, KV tile 32. S^T = mfma(K,Q): lane = q-row.
// O^T = mfma(V,P): acc col = q-row  => softmax, alpha, l all lane-local.
// Cross-half (lane^32) exchange via __shfl_xor ONLY (HW-verified primitive;
// permlane32_swap abandoned after r5/r6 falsified both semantic readings).
__global__ __launch_bounds__(64) void k_attn(
    const f16* __restrict__ Q, const f16* __restrict__ Kg, const f16* __restrict__ Vt,
    const int* __restrict__ amask, const int* __restrict__ pE,
    f16* __restrict__ AO) {
  const int lid = (blockIdx.x & 7) * 512 + (blockIdx.x >> 3);  // XCD swizzle (4096%8==0)
  const int bh = lid >> 6;
  const int qt = 63 - (lid & 63);                              // heavy blocks first
  const int b = bh >> 4, h = bh & 15;
  const int lane = threadIdx.x;
  const int ql = lane & 31;        // q-row (softmax/acc), kv-row (K frag), d (V frag)
  const int hf = lane >> 5;
  const int E = *pE;
  const int irow = qt * 32 + ql;
  constexpr float SCALE = 0.125f * 1.44269504088896f;  // dh^-0.5 * log2(e)

  // Q B-frag (scale folded in): Q[q=ql][k16*16 + hf*8 .. +8]
  f16x8 qf[4];
  {
    const f16* qp = Q + ((size_t)(b * 2048 + irow)) * 1024 + h * 64 + hf * 8;
#pragma unroll
    for (int k16 = 0; k16 < 4; ++k16) {
      f16x8 v = *reinterpret_cast<const f16x8*>(qp + k16 * 16);
#pragma unroll
      for (int e = 0; e < 8; ++e) v[e] = (f16)((float)v[e] * SCALE);
      qf[k16] = v;
    }
  }

  f32x16 acc0 = {}, acc1 = {};
  float mq = -1e30f, lq = 0.f;

  int nkv = qt + 1;
  int ekv = (E + 31) >> 5;
  if (ekv > nkv) nkv = ekv;
  if (nkv > 64) nkv = 64;

  auto LOADK = [&](int jb, f16x8* kf) {
    const f16* kp = Kg + ((size_t)(b * 2048 + jb * 32 + ql)) * 1024 + h * 64 + hf * 8;
#pragma unroll
    for (int k16 = 0; k16 < 4; ++k16)
      kf[k16] = *reinterpret_cast<const f16x8*>(kp + k16 * 16);
  };

  auto BODY = [&](int jb, const f16x8* kc, f16x8* kn) {
    const int kv0 = jb * 32;
    // S^T[kv][q]: 4 chained mfma over d
    f32x16 st = {};
#pragma unroll
    for (int k16 = 0; k16 < 4; ++k16)
      st = __builtin_amdgcn_mfma_f32_32x32x16_f16(kc[k16], qf[k16], st, 0, 0, 0);
    // V A-frag loads (consumed at the end -> latency hidden): vf[dh2*2+kh]
    f16x8 vf[4];
#pragma unroll
    for (int dh2 = 0; dh2 < 2; ++dh2)
#pragma unroll
      for (int kh = 0; kh < 2; ++kh)
        vf[dh2 * 2 + kh] = *reinterpret_cast<const f16x8*>(
            Vt + (size_t)bh * 131072 + (size_t)(dh2 * 32 + ql) * 2048 + kv0 + kh * 16 + hf * 8);
    // amask ballot (bit l (0..31) = column kv0+l valid; upper bits duplicate)
    int av = amask[b * 2048 + kv0 + ql];
    unsigned long long mb = __ballot(av != 0);
    // prefetch next K tile
    int jn = (jb + 1 < nkv) ? jb + 1 : jb;
    LOADK(jn, kn);
    // masking (wave-uniform branch; full tiles with all-ones mask skip entirely)
    bool full = (jb < qt) || ((jb + 1) * 32 <= E);
    if (!full || mb != ~0ull) {
#pragma unroll
      for (int r = 0; r < 16; ++r) {
        int kvl = (r & 3) + 8 * (r >> 2) + 4 * hf;
        int jcol = kv0 + kvl;
        bool vis = full || (jcol <= irow) || (jcol < E);
        vis = vis && (((mb >> kvl) & 1ull) != 0);
        st[r] = vis ? st[r] : -1e30f;
      }
    }
    // row max: in-lane tree + partner-half merge (shfl_xor 32: verified)
    float m01 = fmaxf(fmaxf(st[0], st[1]), fmaxf(st[2], st[3]));
    float m23 = fmaxf(fmaxf(st[4], st[5]), fmaxf(st[6], st[7]));
    float m45 = fmaxf(fmaxf(st[8], st[9]), fmaxf(st[10], st[11]));
    float m67 = fmaxf(fmaxf(st[12], st[13]), fmaxf(st[14], st[15]));
    float mt = fmaxf(fmaxf(m01, m23), fmaxf(m45, m67));
    mt = fmaxf(mt, __shfl_xor(mt, 32, 64));
    // defer-max (T13): skip rescale while growth <= 8 (log2) => P <= 256
    if (!__all(mt - mq <= 8.0f)) {
      float mnew = fmaxf(mq, mt);
      float alpha = fexp2(mq - mnew);
      lq *= alpha;
#pragma unroll
      for (int r = 0; r < 16; ++r) { acc0[r] *= alpha; acc1[r] *= alpha; }
      mq = mnew;
    }
    // P = exp2(st - mq); per-lane partial sum; pack to dwords (kv-consecutive pairs)
    // ownership: dw[t] = kv pair; hf=0: dw0..7 = (0,1)(2,3)(8,9)(10,11)(16,17)(18,19)(24,25)(26,27)
    //            hf=1: dw0..7 = (4,5)(6,7)(12,13)(14,15)(20,21)(22,23)(28,29)(30,31)
    float p[16];
    float ps = 0.f;
#pragma unroll
    for (int r = 0; r < 16; ++r) { p[r] = fexp2(st[r] - mq); ps += p[r]; }
    lq += ps;
    unsigned dw[8];
#pragma unroll
    for (int t = 0; t < 8; ++t)
      dw[t] = __builtin_bit_cast(unsigned, __builtin_amdgcn_cvt_pkrtz(p[2 * t], p[2 * t + 1]));
    // B-fragment element e must hold kv = (kh*16) + hf*8 + e (matching vf's map).
    // pf0 hf=0 needs [own dw0, own dw1, partner dw0, partner dw1]
    // pf0 hf=1 needs [partner dw2, partner dw3, own dw2, own dw3]
    // select-then-shuffle: send what partner needs, one shfl per pair.
    union PF { unsigned u[4]; f16x8 v; } pf0, pf1;
    {
      unsigned sA = hf ? dw[0] : dw[2];
      unsigned sB = hf ? dw[1] : dw[3];
      unsigned rA = (unsigned)__shfl_xor((int)sA, 32, 64);
      unsigned rB = (unsigned)__shfl_xor((int)sB, 32, 64);
      pf0.u[0] = hf ? rA : dw[0];
      pf0.u[1] = hf ? rB : dw[1];
      pf0.u[2] = hf ? dw[2] : rA;
      pf0.u[3] = hf ? dw[3] : rB;
      unsigned sC = hf ? dw[4] : dw[6];
      unsigned sD = hf ? dw[5] : dw[7];
      unsigned rC = (unsigned)__shfl_xor((int)sC, 32, 64);
      unsigned rD = (unsigned)__shfl_xor((int)sD, 32, 64);
      pf1.u[0] = hf ? rC : dw[4];
      pf1.u[1] = hf ? rD : dw[5];
      pf1.u[2] = hf ? dw[6] : rC;
      pf1.u[3] = hf ? dw[7] : rD;
    }
    // O^T += V * P^T  (acc col = q)
    acc0 = __builtin_amdgcn_mfma_f32_32x32x16_f16(vf[0], pf0.v, acc0, 0, 0, 0);
    acc0 = __builtin_amdgcn_mfma_f32_32x32x16_f16(vf[1], pf1.v, acc0, 0, 0, 0);
    acc1 = __builtin_amdgcn_mfma_f32_32x32x16_f16(vf[2], pf0.v, acc1, 0, 0, 0);
    acc1 = __builtin_amdgcn_mfma_f32_32x32x16_f16(vf[3], pf1.v, acc1, 0, 0, 0);
  };

  f16x8 kA[4], kB[4];
  LOADK(0, kA);
  int jb = 0;
  while (true) {
    BODY(jb, kA, kB);
    if (++jb >= nkv) break;
    BODY(jb, kB, kA);
    if (++jb >= nkv) break;
  }

  // merge partner-half partial sums; normalize; write O (rows = q)
  float ltot = lq + __shfl_xor(lq, 32, 64);
  float inv = 1.0f / ltot;
  f16* op = AO + ((size_t)(b * 2048 + irow)) * 1024 + h * 64;
#pragma unroll
  for (int t = 0; t < 4; ++t) {
    int d0 = 8 * t + 4 * hf;
    f16x4 o0, o1;
#pragma unroll
    for (int e = 0; e < 4; ++e) {
      o0[e] = (f16)(acc0[4 * t + e] * inv);
      o1[e] = (f16)(acc1[4 * t + e] * inv);
    }
    *reinterpret_cast<f16x4*>(op + d0) = o0;
    *reinterpret_cast<f16x4*>(op + 32 + d0) = o1;
  }
}

// ---------------- launcher ----------------
extern "C" void kernel_launch(void* const* d_in, const int* in_sizes, int n_in,
                              void* d_out, int out_size, void* d_ws, size_t ws_size,
                              hipStream_t stream) {
  const float* x  = (const float*)d_in[0];
  const float* Wq = (const float*)d_in[1];
  const float* Wk = (const float*)d_in[2];
  const float* Wv = (const float*)d_in[3];
  const float* Wo = (const float*)d_in[4];
  const int* amask = (const int*)d_in[5];
  const int* pE    = (const int*)d_in[6];
  const int* pSkip = (const int*)d_in[7];

  char* ws = (char*)d_ws;
  f16* xb  = (f16*)(ws);
  f16* Wqb = (f16*)(ws + (16u << 20));
  f16* Wkb = (f16*)(ws + (18u << 20));
  f16* Wvb = (f16*)(ws + (20u << 20));
  f16* Wob = (f16*)(ws + (22u << 20));
  f16* Qf  = (f16*)(ws + (24u << 20));
  f16* Kf  = (f16*)(ws + (40u << 20));
  f16* Vf  = (f16*)(ws + (56u << 20));
  f16* Vt  = (f16*)(ws + (72u << 20));
  f16* AO  = xb;

  k_cvt<<<4096, 256, 0, stream>>>(x, xb, 8388608);
  k_cvt<<<512, 256, 0, stream>>>(Wq, Wqb, 1048576);
  k_cvt<<<512, 256, 0, stream>>>(Wk, Wkb, 1048576);
  k_cvt<<<512, 256, 0, stream>>>(Wv, Wvb, 1048576);
  k_cvt<<<512, 256, 0, stream>>>(Wo, Wob, 1048576);
  k_gemm<0><<<dim3(8, 64, 3), 256, 0, stream>>>(xb, Wqb, Wkb, Wvb, Qf, Kf, Vf);
  k_rope<<<16384, 256, 0, stream>>>(Qf, Kf, pE, pSkip);
  k_vtrans<<<dim3(32, 64), 256, 0, stream>>>(Vf, Vt);
  k_attn<<<4096, 64, 0, stream>>>(Qf, Kf, Vt, amask, pE, AO);
  k_gemm<1><<<dim3(8, 64, 1), 256, 0, stream>>>(AO, Wob, Wob, Wob, d_out, d_out, d_out);
}

// Round 8
// 251.898 us; speedup vs baseline: 1.8730x; 1.2152x over previous
//
#include <hip/hip_runtime.h>
#include <cstdint>
#include <cstddef>

typedef _Float16 f16;
typedef _Float16 f16x4 __attribute__((ext_vector_type(4)));
typedef _Float16 f16x8 __attribute__((ext_vector_type(8)));
typedef float f32x4 __attribute__((ext_vector_type(4)));
typedef float f32x16 __attribute__((ext_vector_type(16)));

#define DEVI __device__ __forceinline__

DEVI void gload_lds16(const void* g, void* l) {
  __builtin_amdgcn_global_load_lds(
      (const __attribute__((address_space(1))) void*)g,
      (__attribute__((address_space(3))) void*)l, 16, 0, 0);
}

DEVI float fexp2(float x) { return __builtin_amdgcn_exp2f(x); }

// ---------------- f32 -> f16 convert, 8 elems/thread ----------------
__global__ void k_cvt(const float* __restrict__ in, f16* __restrict__ out, int n) {
  int i = (blockIdx.x * 256 + threadIdx.x) * 8;
  if (i >= n) return;
  const float4* p = reinterpret_cast<const float4*>(in + i);
  float4 a = p[0], b = p[1];
  f16x8 o;
  o[0] = (f16)a.x; o[1] = (f16)a.y; o[2] = (f16)a.z; o[3] = (f16)a.w;
  o[4] = (f16)b.x; o[5] = (f16)b.y; o[6] = (f16)b.z; o[7] = (f16)b.w;
  *reinterpret_cast<f16x8*>(out + i) = o;
}

// ---------------- GEMM: C[M,N] = A[M,K] * B[N,K]^T ----------------
template<int OUTF32>
__global__ __launch_bounds__(256) void k_gemm(
    const f16* __restrict__ A,
    const f16* __restrict__ B0, const f16* __restrict__ B1, const f16* __restrict__ B2,
    void* __restrict__ C0, void* __restrict__ C1, void* __restrict__ C2) {
  constexpr int K = 1024, N = 1024;
  __shared__ f16 As[128 * 64];
  __shared__ f16 Bs[128 * 64];
  const f16* B = (blockIdx.z == 0) ? B0 : ((blockIdx.z == 1) ? B1 : B2);
  void* C = (blockIdx.z == 0) ? C0 : ((blockIdx.z == 1) ? C1 : C2);
  const int tid = threadIdx.x;
  const int lane = tid & 63;
  const int wave = tid >> 6;
  const int wr = wave >> 1, wc = wave & 1;
  const int l15 = lane & 15, l4 = lane >> 4;
  const int m0 = blockIdx.y * 128, n0 = blockIdx.x * 128;
  const int srow = tid >> 3, su = tid & 7;

  f32x4 acc[4][4] = {};

  for (int kt = 0; kt < K; kt += 64) {
    __syncthreads();
#pragma unroll
    for (int q = 0; q < 4; ++q) {
      int r = q * 32 + srow;
      int ce = (su ^ (r & 7)) * 8;
      gload_lds16(A + (size_t)(m0 + r) * K + kt + ce,
                  (char*)As + (q * 256 + (tid & 192)) * 16);
    }
#pragma unroll
    for (int q = 0; q < 4; ++q) {
      int r = q * 32 + srow;
      int ce = (su ^ (r & 7)) * 8;
      gload_lds16(B + (size_t)(n0 + r) * K + kt + ce,
                  (char*)Bs + (q * 256 + (tid & 192)) * 16);
    }
    __syncthreads();
#pragma unroll
    for (int kk = 0; kk < 2; ++kk) {
      f16x8 af[4], bf[4];
#pragma unroll
      for (int mi = 0; mi < 4; ++mi) {
        int r = wr * 64 + mi * 16 + l15;
        int u = (kk * 4 + l4) ^ (r & 7);
        af[mi] = *reinterpret_cast<const f16x8*>((const char*)As + r * 128 + u * 16);
      }
#pragma unroll
      for (int ni = 0; ni < 4; ++ni) {
        int r = wc * 64 + ni * 16 + l15;
        int u = (kk * 4 + l4) ^ (r & 7);
        bf[ni] = *reinterpret_cast<const f16x8*>((const char*)Bs + r * 128 + u * 16);
      }
#pragma unroll
      for (int mi = 0; mi < 4; ++mi)
#pragma unroll
        for (int ni = 0; ni < 4; ++ni)
          acc[mi][ni] = __builtin_amdgcn_mfma_f32_16x16x32_f16(af[mi], bf[ni], acc[mi][ni], 0, 0, 0);
    }
  }
#pragma unroll
  for (int mi = 0; mi < 4; ++mi)
#pragma unroll
    for (int ni = 0; ni < 4; ++ni)
#pragma unroll
      for (int r = 0; r < 4; ++r) {
        int row = m0 + wr * 64 + mi * 16 + l4 * 4 + r;
        int col = n0 + wc * 64 + ni * 16 + l15;
        if (OUTF32)
          ((float*)C)[(size_t)row * N + col] = acc[mi][ni][r];
        else
          ((f16*)C)[(size_t)row * N + col] = (f16)acc[mi][ni][r];
      }
}

// ---------------- RoPE in-place on Q only ----------------
__global__ void k_rope(f16* __restrict__ Q,
                       const int* __restrict__ pE, const int* __restrict__ pSkip) {
  int idx = blockIdx.x * 256 + threadIdx.x;
  int t = idx & 31;
  int h = (idx >> 5) & 15;
  int s = (idx >> 9) & 2047;
  int b = idx >> 20;
  int E = *pE, skip = *pSkip;
  int p;
  if (skip) { if (s < E) return; p = s - E; } else { p = s; }
  float inv_freq = fexp2(-13.28771238f * ((float)t / 32.0f));  // 10000^(-t/32)
  float ang = (float)p * inv_freq;
  float sn, cs;
  sincosf(ang, &sn, &cs);
  size_t base = ((size_t)((b * 2048 + s) * 16 + h)) * 64 + 2 * t;
  union UU { unsigned u; f16 h2[2]; };
  UU qv; qv.u = *reinterpret_cast<const unsigned*>(Q + base);
  float q0 = (float)qv.h2[0], q1 = (float)qv.h2[1];
  qv.h2[0] = (f16)(q0 * cs - q1 * sn);
  qv.h2[1] = (f16)(q1 * cs + q0 * sn);
  *reinterpret_cast<unsigned*>(Q + base) = qv.u;
}

// ---------------- K prep: RoPE + fragment-major repack ----------------
// Kx f16-index: (((b*16+h)*4 + k16)*2048 + s)*16 + hf*8 + e  holds
// roped K[b][s][h][d = k16*16 + hf*8 + e].  k16 = u>>1, hf = u&1.
__global__ __launch_bounds__(256) void k_prepk(
    const f16* __restrict__ Kf, f16* __restrict__ Kx,
    const int* __restrict__ pE, const int* __restrict__ pSkip) {
  int idx = blockIdx.x * 256 + threadIdx.x;  // (b, s, h, u): 1,048,576
  int u = idx & 7;
  int h = (idx >> 3) & 15;
  int s = (idx >> 7) & 2047;
  int b = idx >> 18;
  int E = *pE, skip = *pSkip;
  f16x8 v = *reinterpret_cast<const f16x8*>(
      Kf + ((size_t)((b * 2048 + s) * 16 + h)) * 64 + u * 8);
  if (!(skip && s < E)) {
    int p = skip ? s - E : s;
#pragma unroll
    for (int j = 0; j < 4; ++j) {
      int t = 4 * u + j;
      float inv_freq = fexp2(-13.28771238f * ((float)t / 32.0f));
      float ang = (float)p * inv_freq;
      float sn, cs;
      sincosf(ang, &sn, &cs);
      float x0 = (float)v[2 * j], x1 = (float)v[2 * j + 1];
      v[2 * j]     = (f16)(x0 * cs - x1 * sn);
      v[2 * j + 1] = (f16)(x1 * cs + x0 * sn);
    }
  }
  size_t dst = ((size_t)(((b * 16 + h) * 4 + (u >> 1)) * 2048 + s)) * 16 + (u & 1) * 8;
  *reinterpret_cast<f16x8*>(Kx + dst) = v;
}

// ---------------- V prep: transpose + tau-permuted fragment-major --------
// Vx f16-index: ((((bh*64 + kvblk)*2 + dh2)*2 + kh)*32 + ql)*16 + hf*8 + e
// holds V[b][ s = kvblk*32 + kh*16 + hf*4 + (e&3) + 8*(e>>2) ][h][ d = dh2*32 + ql ].
__global__ __launch_bounds__(256) void k_vtrans(const f16* __restrict__ Vf, f16* __restrict__ Vx) {
  __shared__ f16 tile[64 * 64];
  const int sb = blockIdx.x, bh = blockIdx.y;
  const int b = bh >> 4, h = bh & 15;
  const int tid = threadIdx.x;
#pragma unroll
  for (int it = 0; it < 2; ++it) {
    int i = it * 32 + (tid >> 3);
    int u = tid & 7;
    f16x8 v = *reinterpret_cast<const f16x8*>(
        Vf + ((size_t)(b * 2048 + sb * 64 + i)) * 1024 + h * 64 + u * 8);
    int us = u ^ (i & 7);
    *reinterpret_cast<f16x8*>(&tile[i * 64 + us * 8]) = v;
  }
  __syncthreads();
  const int j = tid >> 2;            // d (0..63)
  const int kvb = (tid >> 1) & 1, kh = tid & 1;
  f16x8 lo, hi;
#pragma unroll
  for (int hf = 0; hf < 2; ++hf)
#pragma unroll
    for (int e = 0; e < 8; ++e) {
      int s5 = kh * 16 + hf * 4 + (e & 3) + ((e >> 2) << 3);
      int i = kvb * 32 + s5;
      f16 val = tile[i * 64 + (((j >> 3) ^ (i & 7)) << 3) + (j & 7)];
      if (hf == 0) lo[e] = val; else hi[e] = val;
    }
  size_t base = ((size_t)((((bh * 64 + sb * 2 + kvb) * 2 + (j >> 5)) * 2 + kh) * 32 + (j & 31))) << 4;
  *reinterpret_cast<f16x8*>(Vx + base) = lo;
  *reinterpret_cast<f16x8*>(Vx + base + 8) = hi;
}

// ---------------- flash attention: 32x32 swapped MFMA, in-register P ------
// Fragment-major Kx/Vx: every K/V load is 64 lanes x 16B CONTIGUOUS.
// tau baked into Vx  =>  P B-fragments are the lane's own dw registers.
// Per-tile cross-lane ops: ONE shfl_xor (max merge). Single K reg buffer.
__global__ __launch_bounds__(64) void k_attn(
    const f16* __restrict__ Q, const f16* __restrict__ Kx, const f16* __restrict__ Vx,
    const int* __restrict__ amask, const int* __restrict__ pE,
    f16* __restrict__ AO) {
  const int lid = (blockIdx.x & 7) * 512 + (blockIdx.x >> 3);  // XCD swizzle (4096%8==0)
  const int bh = lid >> 6;
  const int qt = 63 - (lid & 63);                              // heavy blocks first
  const int b = bh >> 4, h = bh & 15;
  const int lane = threadIdx.x;
  const int ql = lane & 31;
  const int hf = lane >> 5;
  const int E = *pE;
  const int irow = qt * 32 + ql;
  constexpr float SCALE = 0.125f * 1.44269504088896f;  // dh^-0.5 * log2(e)

  f16x8 qf[4];
  {
    const f16* qp = Q + ((size_t)(b * 2048 + irow)) * 1024 + h * 64 + hf * 8;
#pragma unroll
    for (int k16 = 0; k16 < 4; ++k16) {
      f16x8 v = *reinterpret_cast<const f16x8*>(qp + k16 * 16);
#pragma unroll
      for (int e = 0; e < 8; ++e) v[e] = (f16)((float)v[e] * SCALE);
      qf[k16] = v;
    }
  }

  f32x16 acc0 = {}, acc1 = {};
  float mq = -1e30f, lq = 0.f;

  int nkv = qt + 1;
  int ekv = (E + 31) >> 5;
  if (ekv > nkv) nkv = ekv;
  if (nkv > 64) nkv = 64;

  f16x8 kf[4];
#pragma unroll
  for (int k16 = 0; k16 < 4; ++k16)
    kf[k16] = *reinterpret_cast<const f16x8*>(
        Kx + (((size_t)((bh * 4 + k16) * 2048 + ql)) << 4) + hf * 8);

  for (int jb = 0; jb < nkv; ++jb) {
    const int kv0 = jb * 32;
    // S^T[kv][q]: 4 chained mfma over d (lane = q-row col)
    f32x16 st = {};
#pragma unroll
    for (int k16 = 0; k16 < 4; ++k16)
      st = __builtin_amdgcn_mfma_f32_32x32x16_f16(kf[k16], qf[k16], st, 0, 0, 0);
    // V fragment loads (coalesced 1KB runs), consumed at PV
    f16x8 vf[4];
#pragma unroll
    for (int dh2 = 0; dh2 < 2; ++dh2)
#pragma unroll
      for (int kh = 0; kh < 2; ++kh)
        vf[dh2 * 2 + kh] = *reinterpret_cast<const f16x8*>(
            Vx + (((size_t)((((bh * 64 + jb) * 2 + dh2) * 2 + kh) * 32 + ql)) << 4) + hf * 8);
    // amask ballot (bits 0..31 = columns; upper half duplicates)
    int av = amask[b * 2048 + kv0 + ql];
    unsigned long long mb = __ballot(av != 0);
    // prefetch next K tile into the SAME register buffer (kf dead after QK issue)
    if (jb + 1 < nkv) {
#pragma unroll
      for (int k16 = 0; k16 < 4; ++k16)
        kf[k16] = *reinterpret_cast<const f16x8*>(
            Kx + (((size_t)((bh * 4 + k16) * 2048 + kv0 + 32 + ql)) << 4) + hf * 8);
    }
    // masking (wave-uniform skip for full tiles)
    bool full = (jb < qt) || ((jb + 1) * 32 <= E);
    if (!full || mb != ~0ull) {
#pragma unroll
      for (int r = 0; r < 16; ++r) {
        int kvl = (r & 3) + 8 * (r >> 2) + 4 * hf;
        int jcol = kv0 + kvl;
        bool vis = full || (jcol <= irow) || (jcol < E);
        vis = vis && (((mb >> kvl) & 1ull) != 0);
        st[r] = vis ? st[r] : -1e30f;
      }
    }
    // row max: in-lane tree + one cross-half merge
    float m01 = fmaxf(fmaxf(st[0], st[1]), fmaxf(st[2], st[3]));
    float m23 = fmaxf(fmaxf(st[4], st[5]), fmaxf(st[6], st[7]));
    float m45 = fmaxf(fmaxf(st[8], st[9]), fmaxf(st[10], st[11]));
    float m67 = fmaxf(fmaxf(st[12], st[13]), fmaxf(st[14], st[15]));
    float mt = fmaxf(fmaxf(m01, m23), fmaxf(m45, m67));
    mt = fmaxf(mt, __shfl_xor(mt, 32, 64));
    // defer-max (T13): skip rescale while growth <= 8 (log2) => P <= 256
    if (!__all(mt - mq <= 8.0f)) {
      float mnew = fmaxf(mq, mt);
      float alpha = fexp2(mq - mnew);
      lq *= alpha;
#pragma unroll
      for (int r = 0; r < 16; ++r) { acc0[r] *= alpha; acc1[r] *= alpha; }
      mq = mnew;
    }
    // P = exp2(st - mq); pack pairs; B-fragments are OWN dwords (tau layout)
    float p[16];
    float ps = 0.f;
#pragma unroll
    for (int r = 0; r < 16; ++r) { p[r] = fexp2(st[r] - mq); ps += p[r]; }
    lq += ps;
    union PF { unsigned u[4]; f16x8 v; } pf0, pf1;
#pragma unroll
    for (int t = 0; t < 4; ++t) {
      pf0.u[t] = __builtin_bit_cast(unsigned, __builtin_amdgcn_cvt_pkrtz(p[2 * t], p[2 * t + 1]));
      pf1.u[t] = __builtin_bit_cast(unsigned, __builtin_amdgcn_cvt_pkrtz(p[8 + 2 * t], p[9 + 2 * t]));
    }
    // O^T += V * P^T  (acc col = q)
    acc0 = __builtin_amdgcn_mfma_f32_32x32x16_f16(vf[0], pf0.v, acc0, 0, 0, 0);
    acc0 = __builtin_amdgcn_mfma_f32_32x32x16_f16(vf[1], pf1.v, acc0, 0, 0, 0);
    acc1 = __builtin_amdgcn_mfma_f32_32x32x16_f16(vf[2], pf0.v, acc1, 0, 0, 0);
    acc1 = __builtin_amdgcn_mfma_f32_32x32x16_f16(vf[3], pf1.v, acc1, 0, 0, 0);
  }

  // merge partner-half partial sums; normalize; write O (rows = q)
  float ltot = lq + __shfl_xor(lq, 32, 64);
  float inv = 1.0f / ltot;
  f16* op = AO + ((size_t)(b * 2048 + irow)) * 1024 + h * 64;
#pragma unroll
  for (int t = 0; t < 4; ++t) {
    int d0 = 8 * t + 4 * hf;
    f16x4 o0, o1;
#pragma unroll
    for (int e = 0; e < 4; ++e) {
      o0[e] = (f16)(acc0[4 * t + e] * inv);
      o1[e] = (f16)(acc1[4 * t + e] * inv);
    }
    *reinterpret_cast<f16x4*>(op + d0) = o0;
    *reinterpret_cast<f16x4*>(op + 32 + d0) = o1;
  }
}

// ---------------- launcher ----------------
extern "C" void kernel_launch(void* const* d_in, const int* in_sizes, int n_in,
                              void* d_out, int out_size, void* d_ws, size_t ws_size,
                              hipStream_t stream) {
  const float* x  = (const float*)d_in[0];
  const float* Wq = (const float*)d_in[1];
  const float* Wk = (const float*)d_in[2];
  const float* Wv = (const float*)d_in[3];
  const float* Wo = (const float*)d_in[4];
  const int* amask = (const int*)d_in[5];
  const int* pE    = (const int*)d_in[6];
  const int* pSkip = (const int*)d_in[7];

  char* ws = (char*)d_ws;
  f16* xb  = (f16*)(ws);                    // x f16; dead after gemm<0> -> Kx
  f16* Wqb = (f16*)(ws + (16u << 20));
  f16* Wkb = (f16*)(ws + (18u << 20));
  f16* Wvb = (f16*)(ws + (20u << 20));
  f16* Wob = (f16*)(ws + (22u << 20));
  f16* Qf  = (f16*)(ws + (24u << 20));
  f16* Kf  = (f16*)(ws + (40u << 20));      // dead after k_prepk -> AO
  f16* Vf  = (f16*)(ws + (56u << 20));      // dead after k_vtrans
  f16* Vx  = (f16*)(ws + (72u << 20));
  f16* Kx  = xb;
  f16* AO  = Kf;

  k_cvt<<<4096, 256, 0, stream>>>(x, xb, 8388608);
  k_cvt<<<512, 256, 0, stream>>>(Wq, Wqb, 1048576);
  k_cvt<<<512, 256, 0, stream>>>(Wk, Wkb, 1048576);
  k_cvt<<<512, 256, 0, stream>>>(Wv, Wvb, 1048576);
  k_cvt<<<512, 256, 0, stream>>>(Wo, Wob, 1048576);
  k_gemm<0><<<dim3(8, 64, 3), 256, 0, stream>>>(xb, Wqb, Wkb, Wvb, Qf, Kf, Vf);
  k_rope<<<16384, 256, 0, stream>>>(Qf, pE, pSkip);
  k_prepk<<<4096, 256, 0, stream>>>(Kf, Kx, pE, pSkip);
  k_vtrans<<<dim3(32, 64), 256, 0, stream>>>(Vf, Vx);
  k_attn<<<4096, 64, 0, stream>>>(Qf, Kx, Vx, amask, pE, AO);
  k_gemm<1><<<dim3(8, 64, 1), 256, 0, stream>>>(AO, Wob, Wob, Wob, d_out, d_out, d_out);
}

// Round 9
// 245.453 us; speedup vs baseline: 1.9222x; 1.0263x over previous
//
#include <hip/hip_runtime.h>
#include <cstdint>
#include <cstddef>

typedef _Float16 f16;
typedef _Float16 f16x4 __attribute__((ext_vector_type(4)));
typedef _Float16 f16x8 __attribute__((ext_vector_type(8)));
typedef float f32x4 __attribute__((ext_vector_type(4)));
typedef float f32x16 __attribute__((ext_vector_type(16)));

#define DEVI __device__ __forceinline__

DEVI void gload_lds16(const void* g, void* l) {
  __builtin_amdgcn_global_load_lds(
      (const __attribute__((address_space(1))) void*)g,
      (__attribute__((address_space(3))) void*)l, 16, 0, 0);
}

DEVI float fexp2(float x) { return __builtin_amdgcn_exp2f(x); }

// ---------------- f32 -> f16 convert, 8 elems/thread ----------------
__global__ void k_cvt(const float* __restrict__ in, f16* __restrict__ out, int n) {
  int i = (blockIdx.x * 256 + threadIdx.x) * 8;
  if (i >= n) return;
  const float4* p = reinterpret_cast<const float4*>(in + i);
  float4 a = p[0], b = p[1];
  f16x8 o;
  o[0] = (f16)a.x; o[1] = (f16)a.y; o[2] = (f16)a.z; o[3] = (f16)a.w;
  o[4] = (f16)b.x; o[5] = (f16)b.y; o[6] = (f16)b.z; o[7] = (f16)b.w;
  *reinterpret_cast<f16x8*>(out + i) = o;
}

// ---------------- misc prep: sincos table + packed attention mask --------
// sctab[s*32+t] = (cos, sin) of RoPE angle for seq pos s, pair t.
// Rows s<E under skip_phase get (1,0): epilogue rope becomes a no-op there.
// pmask[b*64+jb] bit j = attention_mask[b][jb*32+j].
__global__ void k_misc(const int* __restrict__ amask,
                       const int* __restrict__ pE, const int* __restrict__ pSkip,
                       float2* __restrict__ sctab, unsigned* __restrict__ pmask) {
  int E = *pE, skip = *pSkip;
  if (blockIdx.x < 256) {
    int idx = blockIdx.x * 256 + threadIdx.x;
    int s = idx >> 5, t = idx & 31;
    float c = 1.0f, sn = 0.0f;
    if (!(skip && s < E)) {
      int p = skip ? s - E : s;
      float inv_freq = powf(10000.0f, -(float)t / 32.0f);
      sincosf((float)p * inv_freq, &sn, &c);
    }
    sctab[idx] = make_float2(c, sn);
  } else {
    int tid = threadIdx.x;           // 0..255 -> (b, jb)
    int b = tid >> 6, jb = tid & 63;
    unsigned bits = 0;
    for (int j = 0; j < 32; ++j)
      bits |= (amask[b * 2048 + jb * 32 + j] != 0 ? 1u : 0u) << j;
    pmask[tid] = bits;
  }
}

// ---------------- GEMM: C[M,N] = A[M,K] * B[N,K]^T ----------------
// MODE 1: single output, f32 (final Wo projection).
// MODE 2: fused QKV. z=0: rope -> Qf (row-major). z=1: rope -> Kx
//         (fragment-major). z=2: -> Vx (tau-permuted fragment-major).
// RoPE applied to the f32 accumulator: pair partner = adjacent column =
// adjacent lane (l15^1) -> shfl_xor(val,1).
template<int MODE>
__global__ __launch_bounds__(256) void k_gemm(
    const f16* __restrict__ A,
    const f16* __restrict__ B0, const f16* __restrict__ B1, const f16* __restrict__ B2,
    void* __restrict__ C0, void* __restrict__ C1, void* __restrict__ C2,
    const float2* __restrict__ sctab) {
  constexpr int K = 1024, N = 1024;
  __shared__ f16 As[128 * 64];
  __shared__ f16 Bs[128 * 64];
  const f16* B = (blockIdx.z == 0) ? B0 : ((blockIdx.z == 1) ? B1 : B2);
  const int tid = threadIdx.x;
  const int lane = tid & 63;
  const int wave = tid >> 6;
  const int wr = wave >> 1, wc = wave & 1;
  const int l15 = lane & 15, l4 = lane >> 4;
  const int m0 = blockIdx.y * 128, n0 = blockIdx.x * 128;
  const int srow = tid >> 3, su = tid & 7;

  f32x4 acc[4][4] = {};

  for (int kt = 0; kt < K; kt += 64) {
    __syncthreads();
#pragma unroll
    for (int q = 0; q < 4; ++q) {
      int r = q * 32 + srow;
      int ce = (su ^ (r & 7)) * 8;
      gload_lds16(A + (size_t)(m0 + r) * K + kt + ce,
                  (char*)As + (q * 256 + (tid & 192)) * 16);
    }
#pragma unroll
    for (int q = 0; q < 4; ++q) {
      int r = q * 32 + srow;
      int ce = (su ^ (r & 7)) * 8;
      gload_lds16(B + (size_t)(n0 + r) * K + kt + ce,
                  (char*)Bs + (q * 256 + (tid & 192)) * 16);
    }
    __syncthreads();
#pragma unroll
    for (int kk = 0; kk < 2; ++kk) {
      f16x8 af[4], bf[4];
#pragma unroll
      for (int mi = 0; mi < 4; ++mi) {
        int r = wr * 64 + mi * 16 + l15;
        int u = (kk * 4 + l4) ^ (r & 7);
        af[mi] = *reinterpret_cast<const f16x8*>((const char*)As + r * 128 + u * 16);
      }
#pragma unroll
      for (int ni = 0; ni < 4; ++ni) {
        int r = wc * 64 + ni * 16 + l15;
        int u = (kk * 4 + l4) ^ (r & 7);
        bf[ni] = *reinterpret_cast<const f16x8*>((const char*)Bs + r * 128 + u * 16);
      }
#pragma unroll
      for (int mi = 0; mi < 4; ++mi)
#pragma unroll
        for (int ni = 0; ni < 4; ++ni)
          acc[mi][ni] = __builtin_amdgcn_mfma_f32_16x16x32_f16(af[mi], bf[ni], acc[mi][ni], 0, 0, 0);
    }
  }

  if (MODE == 1) {
#pragma unroll
    for (int mi = 0; mi < 4; ++mi)
#pragma unroll
      for (int ni = 0; ni < 4; ++ni)
#pragma unroll
        for (int r = 0; r < 4; ++r) {
          int row = m0 + wr * 64 + mi * 16 + l4 * 4 + r;
          int col = n0 + wc * 64 + ni * 16 + l15;
          ((float*)C0)[(size_t)row * N + col] = acc[mi][ni][r];
        }
  } else {
    const int z = blockIdx.z;
    f16* Qf = (f16*)C0;
    f16* Kx = (f16*)C1;
    f16* Vx = (f16*)C2;
#pragma unroll
    for (int mi = 0; mi < 4; ++mi)
#pragma unroll
      for (int ni = 0; ni < 4; ++ni)
#pragma unroll
        for (int r = 0; r < 4; ++r) {
          int row = m0 + wr * 64 + mi * 16 + l4 * 4 + r;  // b*2048 + s
          int col = n0 + wc * 64 + ni * 16 + l15;         // h*64 + dd
          int s = row & 2047, b = row >> 11;
          int dd = (ni * 16 + l15);                       // col & 63
          int h = col >> 6;
          float val = acc[mi][ni][r];
          if (z <= 1) {
            // RoPE: even col holds x0, odd holds x1 (partner = lane^1)
            float pv = __shfl_xor(val, 1, 64);
            float2 cs = sctab[s * 32 + (dd >> 1)];
            val = val * cs.x + ((l15 & 1) ? pv * cs.y : -pv * cs.y);
            if (z == 0) {
              Qf[(size_t)row * 1024 + col] = (f16)val;
            } else {
              int k16 = dd >> 4, hf = (dd >> 3) & 1, e = dd & 7;
              Kx[(((size_t)((b * 16 + h) * 4 + k16) * 2048 + s) << 4) + hf * 8 + e] = (f16)val;
            }
          } else {
            // Vx: s -> (kvblk, kh, hf, e) via tau; d -> (dh2, ql)
            int kvblk = s >> 5, s5 = s & 31;
            int kh = s5 >> 4, s4 = s5 & 15;
            int hf = (s4 >> 2) & 1;
            int e = (s4 & 3) | (((s4 >> 3) & 1) << 2);
            int ql = dd & 31, dh2 = dd >> 5;
            size_t idx = (((size_t)((((b * 16 + h) * 64 + kvblk) * 2 + dh2) * 2 + kh) * 32 + ql) << 4)
                         + hf * 8 + e;
            Vx[idx] = (f16)val;
          }
        }
  }
}

// ---------------- flash attention: 32x32 swapped MFMA, in-register P ------
// Fragment-major Kx/Vx: every K/V load is 64 lanes x 16B CONTIGUOUS.
// tau baked into Vx => P B-fragments are the lane's own dw registers.
// Per-tile cross-lane ops: ONE shfl_xor (max merge). Scalar packed mask.
__global__ __launch_bounds__(64) void k_attn(
    const f16* __restrict__ Q, const f16* __restrict__ Kx, const f16* __restrict__ Vx,
    const unsigned* __restrict__ pmask, const int* __restrict__ pE,
    f16* __restrict__ AO) {
  const int lid = (blockIdx.x & 7) * 512 + (blockIdx.x >> 3);  // XCD swizzle (4096%8==0)
  const int bh = lid >> 6;
  const int qt = 63 - (lid & 63);                              // heavy blocks first
  const int b = bh >> 4, h = bh & 15;
  const int lane = threadIdx.x;
  const int ql = lane & 31;
  const int hf = lane >> 5;
  const int E = *pE;
  const int irow = qt * 32 + ql;
  constexpr float SCALE = 0.125f * 1.44269504088896f;  // dh^-0.5 * log2(e)

  f16x8 qf[4];
  {
    const f16* qp = Q + ((size_t)(b * 2048 + irow)) * 1024 + h * 64 + hf * 8;
#pragma unroll
    for (int k16 = 0; k16 < 4; ++k16) {
      f16x8 v = *reinterpret_cast<const f16x8*>(qp + k16 * 16);
#pragma unroll
      for (int e = 0; e < 8; ++e) v[e] = (f16)((float)v[e] * SCALE);
      qf[k16] = v;
    }
  }

  f32x16 acc0 = {}, acc1 = {};
  float mq = -1e30f, lq = 0.f;

  int nkv = qt + 1;
  int ekv = (E + 31) >> 5;
  if (ekv > nkv) nkv = ekv;
  if (nkv > 64) nkv = 64;

  f16x8 kf[4];
#pragma unroll
  for (int k16 = 0; k16 < 4; ++k16)
    kf[k16] = *reinterpret_cast<const f16x8*>(
        Kx + (((size_t)((bh * 4 + k16) * 2048 + ql)) << 4) + hf * 8);

  for (int jb = 0; jb < nkv; ++jb) {
    const int kv0 = jb * 32;
    // S^T[kv][q]: 4 chained mfma over d (lane = q-row col)
    f32x16 st = {};
#pragma unroll
    for (int k16 = 0; k16 < 4; ++k16)
      st = __builtin_amdgcn_mfma_f32_32x32x16_f16(kf[k16], qf[k16], st, 0, 0, 0);
    // V fragment loads (coalesced 1KB runs), consumed at PV
    f16x8 vf[4];
#pragma unroll
    for (int dh2 = 0; dh2 < 2; ++dh2)
#pragma unroll
      for (int kh = 0; kh < 2; ++kh)
        vf[dh2 * 2 + kh] = *reinterpret_cast<const f16x8*>(
            Vx + (((size_t)((((bh * 64 + jb) * 2 + dh2) * 2 + kh) * 32 + ql)) << 4) + hf * 8);
    // scalar packed column mask for this tile
    unsigned pm = pmask[b * 64 + jb];
    // prefetch next K tile into the SAME register buffer (kf dead after QK issue)
    if (jb + 1 < nkv) {
#pragma unroll
      for (int k16 = 0; k16 < 4; ++k16)
        kf[k16] = *reinterpret_cast<const f16x8*>(
            Kx + (((size_t)((bh * 4 + k16) * 2048 + kv0 + 32 + ql)) << 4) + hf * 8);
    }
    // masking (wave-uniform skip for full tiles)
    bool full = ((jb < qt) || ((jb + 1) * 32 <= E)) && (pm == 0xffffffffu);
    if (!full) {
#pragma unroll
      for (int r = 0; r < 16; ++r) {
        int kvl = (r & 3) + 8 * (r >> 2) + 4 * hf;
        int jcol = kv0 + kvl;
        bool vis = ((jcol <= irow) || (jcol < E)) && (((pm >> kvl) & 1u) != 0);
        st[r] = vis ? st[r] : -1e30f;
      }
    }
    // row max: in-lane tree + one cross-half merge
    float m01 = fmaxf(fmaxf(st[0], st[1]), fmaxf(st[2], st[3]));
    float m23 = fmaxf(fmaxf(st[4], st[5]), fmaxf(st[6], st[7]));
    float m45 = fmaxf(fmaxf(st[8], st[9]), fmaxf(st[10], st[11]));
    float m67 = fmaxf(fmaxf(st[12], st[13]), fmaxf(st[14], st[15]));
    float mt = fmaxf(fmaxf(m01, m23), fmaxf(m45, m67));
    mt = fmaxf(mt, __shfl_xor(mt, 32, 64));
    // defer-max (T13): skip rescale while growth <= 8 (log2) => P <= 256
    if (!__all(mt - mq <= 8.0f)) {
      float mnew = fmaxf(mq, mt);
      float alpha = fexp2(mq - mnew);
      lq *= alpha;
#pragma unroll
      for (int r = 0; r < 16; ++r) { acc0[r] *= alpha; acc1[r] *= alpha; }
      mq = mnew;
    }
    // P = exp2(st - mq); pack pairs; B-fragments are OWN dwords (tau layout)
    float p[16];
    float ps = 0.f;
#pragma unroll
    for (int r = 0; r < 16; ++r) { p[r] = fexp2(st[r] - mq); ps += p[r]; }
    lq += ps;
    union PF { unsigned u[4]; f16x8 v; } pf0, pf1;
#pragma unroll
    for (int t = 0; t < 4; ++t) {
      pf0.u[t] = __builtin_bit_cast(unsigned, __builtin_amdgcn_cvt_pkrtz(p[2 * t], p[2 * t + 1]));
      pf1.u[t] = __builtin_bit_cast(unsigned, __builtin_amdgcn_cvt_pkrtz(p[8 + 2 * t], p[9 + 2 * t]));
    }
    // O^T += V * P^T  (acc col = q)
    acc0 = __builtin_amdgcn_mfma_f32_32x32x16_f16(vf[0], pf0.v, acc0, 0, 0, 0);
    acc0 = __builtin_amdgcn_mfma_f32_32x32x16_f16(vf[1], pf1.v, acc0, 0, 0, 0);
    acc1 = __builtin_amdgcn_mfma_f32_32x32x16_f16(vf[2], pf0.v, acc1, 0, 0, 0);
    acc1 = __builtin_amdgcn_mfma_f32_32x32x16_f16(vf[3], pf1.v, acc1, 0, 0, 0);
  }

  // merge partner-half partial sums; normalize; write O (rows = q)
  float ltot = lq + __shfl_xor(lq, 32, 64);
  float inv = 1.0f / ltot;
  f16* op = AO + ((size_t)(b * 2048 + irow)) * 1024 + h * 64;
#pragma unroll
  for (int t = 0; t < 4; ++t) {
    int d0 = 8 * t + 4 * hf;
    f16x4 o0, o1;
#pragma unroll
    for (int e = 0; e < 4; ++e) {
      o0[e] = (f16)(acc0[4 * t + e] * inv);
      o1[e] = (f16)(acc1[4 * t + e] * inv);
    }
    *reinterpret_cast<f16x4*>(op + d0) = o0;
    *reinterpret_cast<f16x4*>(op + 32 + d0) = o1;
  }
}

// ---------------- launcher ----------------
extern "C" void kernel_launch(void* const* d_in, const int* in_sizes, int n_in,
                              void* d_out, int out_size, void* d_ws, size_t ws_size,
                              hipStream_t stream) {
  const float* x  = (const float*)d_in[0];
  const float* Wq = (const float*)d_in[1];
  const float* Wk = (const float*)d_in[2];
  const float* Wv = (const float*)d_in[3];
  const float* Wo = (const float*)d_in[4];
  const int* amask = (const int*)d_in[5];
  const int* pE    = (const int*)d_in[6];
  const int* pSkip = (const int*)d_in[7];

  char* ws = (char*)d_ws;
  f16* xb   = (f16*)(ws);                   // x f16; dead after gemm<2> -> AO
  f16* Wqb  = (f16*)(ws + (16u << 20));
  f16* Wkb  = (f16*)(ws + (18u << 20));
  f16* Wvb  = (f16*)(ws + (20u << 20));
  f16* Wob  = (f16*)(ws + (22u << 20));
  f16* Qf   = (f16*)(ws + (24u << 20));
  f16* Kx   = (f16*)(ws + (40u << 20));
  f16* Vx   = (f16*)(ws + (56u << 20));
  float2* sctab = (float2*)(ws + (72u << 20));   // 512 KB
  unsigned* pmask = (unsigned*)(ws + (73u << 20));
  f16* AO   = xb;

  k_misc<<<257, 256, 0, stream>>>(amask, pE, pSkip, sctab, pmask);
  k_cvt<<<4096, 256, 0, stream>>>(x, xb, 8388608);
  k_cvt<<<512, 256, 0, stream>>>(Wq, Wqb, 1048576);
  k_cvt<<<512, 256, 0, stream>>>(Wk, Wkb, 1048576);
  k_cvt<<<512, 256, 0, stream>>>(Wv, Wvb, 1048576);
  k_cvt<<<512, 256, 0, stream>>>(Wo, Wob, 1048576);
  // QKV projections fused with RoPE + fragment-major repack
  k_gemm<2><<<dim3(8, 64, 3), 256, 0, stream>>>(xb, Wqb, Wkb, Wvb, Qf, Kx, Vx, sctab);
  k_attn<<<4096, 64, 0, stream>>>(Qf, Kx, Vx, pmask, pE, AO);
  // output projection -> fp32 d_out
  k_gemm<1><<<dim3(8, 64, 1), 256, 0, stream>>>(AO, Wob, Wob, Wob, d_out, d_out, d_out, nullptr);
}

// Round 10
// 197.869 us; speedup vs baseline: 2.3844x; 1.2405x over previous
//
#include <hip/hip_runtime.h>
#include <cstdint>
#include <cstddef>

typedef _Float16 f16;
typedef _Float16 f16x4 __attribute__((ext_vector_type(4)));
typedef _Float16 f16x8 __attribute__((ext_vector_type(8)));
typedef float f32x4 __attribute__((ext_vector_type(4)));
typedef float f32x16 __attribute__((ext_vector_type(16)));

#define DEVI __device__ __forceinline__

DEVI void gload_lds16(const void* g, void* l) {
  __builtin_amdgcn_global_load_lds(
      (const __attribute__((address_space(1))) void*)g,
      (__attribute__((address_space(3))) void*)l, 16, 0, 0);
}

DEVI float fexp2(float x) { return __builtin_amdgcn_exp2f(x); }

// ---------------- f32 -> f16 convert, 8 elems/thread ----------------
__global__ void k_cvt(const float* __restrict__ in, f16* __restrict__ out, int n) {
  int i = (blockIdx.x * 256 + threadIdx.x) * 8;
  if (i >= n) return;
  const float4* p = reinterpret_cast<const float4*>(in + i);
  float4 a = p[0], b = p[1];
  f16x8 o;
  o[0] = (f16)a.x; o[1] = (f16)a.y; o[2] = (f16)a.z; o[3] = (f16)a.w;
  o[4] = (f16)b.x; o[5] = (f16)b.y; o[6] = (f16)b.z; o[7] = (f16)b.w;
  *reinterpret_cast<f16x8*>(out + i) = o;
}

// 4 weight matrices in one launch (1 MB f32 each)
__global__ void k_cvtw(const float* __restrict__ w0, const float* __restrict__ w1,
                       const float* __restrict__ w2, const float* __restrict__ w3,
                       f16* __restrict__ o0, f16* __restrict__ o1,
                       f16* __restrict__ o2, f16* __restrict__ o3) {
  int seg = blockIdx.x >> 9;
  const float* in = (seg == 0) ? w0 : (seg == 1) ? w1 : (seg == 2) ? w2 : w3;
  f16* out = (seg == 0) ? o0 : (seg == 1) ? o1 : (seg == 2) ? o2 : o3;
  int i = ((blockIdx.x & 511) * 256 + threadIdx.x) * 8;
  const float4* p = reinterpret_cast<const float4*>(in + i);
  float4 a = p[0], b = p[1];
  f16x8 o;
  o[0] = (f16)a.x; o[1] = (f16)a.y; o[2] = (f16)a.z; o[3] = (f16)a.w;
  o[4] = (f16)b.x; o[5] = (f16)b.y; o[6] = (f16)b.z; o[7] = (f16)b.w;
  *reinterpret_cast<f16x8*>(out + i) = o;
}

// ---------------- misc prep: sincos table + packed attention mask --------
__global__ void k_misc(const int* __restrict__ amask,
                       const int* __restrict__ pE, const int* __restrict__ pSkip,
                       float2* __restrict__ sctab, unsigned* __restrict__ pmask) {
  int E = *pE, skip = *pSkip;
  if (blockIdx.x < 256) {
    int idx = blockIdx.x * 256 + threadIdx.x;
    int s = idx >> 5, t = idx & 31;
    float c = 1.0f, sn = 0.0f;
    if (!(skip && s < E)) {
      int p = skip ? s - E : s;
      float inv_freq = powf(10000.0f, -(float)t / 32.0f);
      sincosf((float)p * inv_freq, &sn, &c);
    }
    sctab[idx] = make_float2(c, sn);
  } else {
    int tid = threadIdx.x;
    int b = tid >> 6, jb = tid & 63;
    unsigned bits = 0;
    for (int j = 0; j < 32; ++j)
      bits |= (amask[b * 2048 + jb * 32 + j] != 0 ? 1u : 0u) << j;
    pmask[tid] = bits;
  }
}

// ---------------- GEMM: C[M,N] = A[M,K] * B[N,K]^T ----------------
// 1-D grid, m-slab XCD map: xcd = lid&7 owns m-panels [xcd*8, xcd*8+8)
// (2 MB of A -> resident in that XCD's private L2 across all n,z).
// MODE 1: f32 row-major out (Wo projection), grid 512.
// MODE 2: fused QKV, grid 1536. z=0: rope -> Qf direct. z=1: rope -> Kx
//   fragment-major via LDS repack. z=2: -> Vx tau-permuted via LDS repack.
template<int MODE>
__global__ __launch_bounds__(256) void k_gemm(
    const f16* __restrict__ A,
    const f16* __restrict__ B0, const f16* __restrict__ B1, const f16* __restrict__ B2,
    void* __restrict__ C0, void* __restrict__ C1, void* __restrict__ C2,
    const float2* __restrict__ sctab) {
  constexpr int K = 1024, N = 1024;
  __shared__ char smem[32768];
  f16* As = (f16*)smem;
  f16* Bs = (f16*)(smem + 16384);
  const int lid = blockIdx.x;
  const int xcd = lid & 7;
  int z, mp, n;
  if (MODE == 1) {
    int c = lid >> 3;
    mp = xcd * 8 + (c & 7);
    n = c >> 3;
    z = 0;
  } else {
    int c = lid >> 3;
    mp = xcd * 8 + (c & 7);
    n = (c >> 3) & 7;
    z = c >> 6;
  }
  const f16* B = (z == 0) ? B0 : ((z == 1) ? B1 : B2);
  const int tid = threadIdx.x;
  const int lane = tid & 63;
  const int wave = tid >> 6;
  const int wr = wave >> 1, wc = wave & 1;
  const int l15 = lane & 15, l4 = lane >> 4;
  const int m0 = mp * 128, n0 = n * 128;
  const int srow = tid >> 3, su = tid & 7;

  f32x4 acc[4][4] = {};

  for (int kt = 0; kt < K; kt += 64) {
    __syncthreads();
#pragma unroll
    for (int q = 0; q < 4; ++q) {
      int r = q * 32 + srow;
      int ce = (su ^ (r & 7)) * 8;
      gload_lds16(A + (size_t)(m0 + r) * K + kt + ce,
                  (char*)As + (q * 256 + (tid & 192)) * 16);
    }
#pragma unroll
    for (int q = 0; q < 4; ++q) {
      int r = q * 32 + srow;
      int ce = (su ^ (r & 7)) * 8;
      gload_lds16(B + (size_t)(n0 + r) * K + kt + ce,
                  (char*)Bs + (q * 256 + (tid & 192)) * 16);
    }
    __syncthreads();
#pragma unroll
    for (int kk = 0; kk < 2; ++kk) {
      f16x8 af[4], bf[4];
#pragma unroll
      for (int mi = 0; mi < 4; ++mi) {
        int r = wr * 64 + mi * 16 + l15;
        int u = (kk * 4 + l4) ^ (r & 7);
        af[mi] = *reinterpret_cast<const f16x8*>((const char*)As + r * 128 + u * 16);
      }
#pragma unroll
      for (int ni = 0; ni < 4; ++ni) {
        int r = wc * 64 + ni * 16 + l15;
        int u = (kk * 4 + l4) ^ (r & 7);
        bf[ni] = *reinterpret_cast<const f16x8*>((const char*)Bs + r * 128 + u * 16);
      }
#pragma unroll
      for (int mi = 0; mi < 4; ++mi)
#pragma unroll
        for (int ni = 0; ni < 4; ++ni)
          acc[mi][ni] = __builtin_amdgcn_mfma_f32_16x16x32_f16(af[mi], bf[ni], acc[mi][ni], 0, 0, 0);
    }
  }

  if (MODE == 1) {
#pragma unroll
    for (int mi = 0; mi < 4; ++mi)
#pragma unroll
      for (int ni = 0; ni < 4; ++ni)
#pragma unroll
        for (int r = 0; r < 4; ++r) {
          int row = m0 + wr * 64 + mi * 16 + l4 * 4 + r;
          int col = n0 + wc * 64 + ni * 16 + l15;
          ((float*)C0)[(size_t)row * N + col] = acc[mi][ni][r];
        }
    return;
  }

  f16* Qf = (f16*)C0;
  f16* Kx = (f16*)C1;
  f16* Vx = (f16*)C2;

  if (z == 0) {
    // rope -> Qf row-major (direct; pattern unchanged from r9)
#pragma unroll
    for (int mi = 0; mi < 4; ++mi)
#pragma unroll
      for (int ni = 0; ni < 4; ++ni)
#pragma unroll
        for (int r = 0; r < 4; ++r) {
          int row = m0 + wr * 64 + mi * 16 + l4 * 4 + r;
          int col = n0 + wc * 64 + ni * 16 + l15;
          int s = row & 2047;
          int dd = col & 63;
          float val = acc[mi][ni][r];
          float pv = __shfl_xor(val, 1, 64);
          float2 cs = sctab[s * 32 + (dd >> 1)];
          val = val * cs.x + ((l15 & 1) ? pv * cs.y : -pv * cs.y);
          Qf[(size_t)row * 1024 + col] = (f16)val;
        }
    return;
  }

  __syncthreads();  // done reading As/Bs everywhere; reuse as C-tile
  f16* Ct = (f16*)smem;

  if (z == 1) {
    // rope in reg, stage row-major swizzled, emit 16B fragment-major stores
#pragma unroll
    for (int mi = 0; mi < 4; ++mi)
#pragma unroll
      for (int ni = 0; ni < 4; ++ni)
#pragma unroll
        for (int r = 0; r < 4; ++r) {
          int sl = wr * 64 + mi * 16 + l4 * 4 + r;
          int cl = wc * 64 + ni * 16 + l15;
          int s = (m0 + sl) & 2047;
          float val = acc[mi][ni][r];
          float pv = __shfl_xor(val, 1, 64);
          float2 cs = sctab[s * 32 + ((cl & 63) >> 1)];
          val = val * cs.x + ((l15 & 1) ? pv * cs.y : -pv * cs.y);
          *(f16*)((char*)Ct + sl * 256 + (((cl >> 3) ^ (sl & 15)) << 4) + (cl & 7) * 2) = (f16)val;
        }
    __syncthreads();
#pragma unroll
    for (int it = 0; it < 8; ++it) {
      int it2 = wave * 8 + it;          // (h2, k16, hf, sh)
      int h2 = it2 >> 4, k16 = (it2 >> 2) & 3, hf = (it2 >> 1) & 1, sh = it2 & 1;
      int sl = sh * 64 + lane;
      int cl = h2 * 64 + k16 * 16 + hf * 8;
      f16x8 v = *(const f16x8*)((const char*)Ct + sl * 256 + (((cl >> 3) ^ (sl & 15)) << 4));
      int sg = m0 + sl;
      int b = sg >> 11, s = sg & 2047;
      int h = (n0 >> 6) + h2;
      *reinterpret_cast<f16x8*>(
          Kx + (((size_t)((b * 16 + h) * 4 + k16) * 2048 + s) << 4) + hf * 8) = v;
    }
  } else {
    // stage col-major swizzled (4 consecutive s packed per write), emit Vx
#pragma unroll
    for (int mi = 0; mi < 4; ++mi)
#pragma unroll
      for (int ni = 0; ni < 4; ++ni) {
        int sl = wr * 64 + mi * 16 + l4 * 4;
        int cl = wc * 64 + ni * 16 + l15;
        f16x4 pk;
#pragma unroll
        for (int r = 0; r < 4; ++r) pk[r] = (f16)acc[mi][ni][r];
        *(f16x4*)((char*)Ct + cl * 256 + ((((sl >> 2) ^ (cl & 31))) << 3)) = pk;
      }
    __syncthreads();
#pragma unroll
    for (int it = 0; it < 8; ++it) {
      int it2 = wave * 8 + it;          // (hh, dh2, kvb, half)
      int hh = it2 >> 4, dh2 = (it2 >> 3) & 1, kvb = (it2 >> 1) & 3, hf = it2 & 1;
      int kh = lane >> 5, ql = lane & 31;
      int cl = hh * 64 + dh2 * 32 + ql;
      int s0 = kvb * 32 + kh * 16 + hf * 4;
      f16x4 a = *(const f16x4*)((const char*)Ct + cl * 256 + (((s0 >> 2) ^ (cl & 31)) << 3));
      f16x4 c = *(const f16x4*)((const char*)Ct + cl * 256 + ((((s0 + 8) >> 2) ^ (cl & 31)) << 3));
      f16x8 v;
#pragma unroll
      for (int e = 0; e < 4; ++e) { v[e] = a[e]; v[4 + e] = c[e]; }
      int b = m0 >> 11;
      int kvblk = ((m0 & 2047) >> 5) + kvb;
      int h = (n0 >> 6) + hh;
      size_t idx = (((size_t)(((b * 16 + h) * 64 + kvblk) * 2 + dh2) * 2 + kh) * 32 + ql) << 4;
      *reinterpret_cast<f16x8*>(Vx + idx + hf * 8) = v;
    }
  }
}

// ---------------- flash attention: 32x32 swapped MFMA, in-register P ------
__global__ __launch_bounds__(64) void k_attn(
    const f16* __restrict__ Q, const f16* __restrict__ Kx, const f16* __restrict__ Vx,
    const unsigned* __restrict__ pmask, const int* __restrict__ pE,
    f16* __restrict__ AO) {
  const int lid = (blockIdx.x & 7) * 512 + (blockIdx.x >> 3);  // XCD swizzle (4096%8==0)
  const int bh = lid >> 6;
  const int qt = 63 - (lid & 63);                              // heavy blocks first
  const int b = bh >> 4, h = bh & 15;
  const int lane = threadIdx.x;
  const int ql = lane & 31;
  const int hf = lane >> 5;
  const int E = *pE;
  const int irow = qt * 32 + ql;
  constexpr float SCALE = 0.125f * 1.44269504088896f;  // dh^-0.5 * log2(e)

  f16x8 qf[4];
  {
    const f16* qp = Q + ((size_t)(b * 2048 + irow)) * 1024 + h * 64 + hf * 8;
#pragma unroll
    for (int k16 = 0; k16 < 4; ++k16) {
      f16x8 v = *reinterpret_cast<const f16x8*>(qp + k16 * 16);
#pragma unroll
      for (int e = 0; e < 8; ++e) v[e] = (f16)((float)v[e] * SCALE);
      qf[k16] = v;
    }
  }

  f32x16 acc0 = {}, acc1 = {};
  float mq = -1e30f, lq = 0.f;

  int nkv = qt + 1;
  int ekv = (E + 31) >> 5;
  if (ekv > nkv) nkv = ekv;
  if (nkv > 64) nkv = 64;

  f16x8 kf[4];
#pragma unroll
  for (int k16 = 0; k16 < 4; ++k16)
    kf[k16] = *reinterpret_cast<const f16x8*>(
        Kx + (((size_t)((bh * 4 + k16) * 2048 + ql)) << 4) + hf * 8);

  for (int jb = 0; jb < nkv; ++jb) {
    const int kv0 = jb * 32;
    f32x16 st = {};
#pragma unroll
    for (int k16 = 0; k16 < 4; ++k16)
      st = __builtin_amdgcn_mfma_f32_32x32x16_f16(kf[k16], qf[k16], st, 0, 0, 0);
    f16x8 vf[4];
#pragma unroll
    for (int dh2 = 0; dh2 < 2; ++dh2)
#pragma unroll
      for (int kh = 0; kh < 2; ++kh)
        vf[dh2 * 2 + kh] = *reinterpret_cast<const f16x8*>(
            Vx + (((size_t)((((bh * 64 + jb) * 2 + dh2) * 2 + kh) * 32 + ql)) << 4) + hf * 8);
    unsigned pm = pmask[b * 64 + jb];
    if (jb + 1 < nkv) {
#pragma unroll
      for (int k16 = 0; k16 < 4; ++k16)
        kf[k16] = *reinterpret_cast<const f16x8*>(
            Kx + (((size_t)((bh * 4 + k16) * 2048 + kv0 + 32 + ql)) << 4) + hf * 8);
    }
    bool full = ((jb < qt) || ((jb + 1) * 32 <= E)) && (pm == 0xffffffffu);
    if (!full) {
#pragma unroll
      for (int r = 0; r < 16; ++r) {
        int kvl = (r & 3) + 8 * (r >> 2) + 4 * hf;
        int jcol = kv0 + kvl;
        bool vis = ((jcol <= irow) || (jcol < E)) && (((pm >> kvl) & 1u) != 0);
        st[r] = vis ? st[r] : -1e30f;
      }
    }
    float m01 = fmaxf(fmaxf(st[0], st[1]), fmaxf(st[2], st[3]));
    float m23 = fmaxf(fmaxf(st[4], st[5]), fmaxf(st[6], st[7]));
    float m45 = fmaxf(fmaxf(st[8], st[9]), fmaxf(st[10], st[11]));
    float m67 = fmaxf(fmaxf(st[12], st[13]), fmaxf(st[14], st[15]));
    float mt = fmaxf(fmaxf(m01, m23), fmaxf(m45, m67));
    mt = fmaxf(mt, __shfl_xor(mt, 32, 64));
    if (!__all(mt - mq <= 8.0f)) {
      float mnew = fmaxf(mq, mt);
      float alpha = fexp2(mq - mnew);
      lq *= alpha;
#pragma unroll
      for (int r = 0; r < 16; ++r) { acc0[r] *= alpha; acc1[r] *= alpha; }
      mq = mnew;
    }
    float p[16];
    float ps = 0.f;
#pragma unroll
    for (int r = 0; r < 16; ++r) { p[r] = fexp2(st[r] - mq); ps += p[r]; }
    lq += ps;
    union PF { unsigned u[4]; f16x8 v; } pf0, pf1;
#pragma unroll
    for (int t = 0; t < 4; ++t) {
      pf0.u[t] = __builtin_bit_cast(unsigned, __builtin_amdgcn_cvt_pkrtz(p[2 * t], p[2 * t + 1]));
      pf1.u[t] = __builtin_bit_cast(unsigned, __builtin_amdgcn_cvt_pkrtz(p[8 + 2 * t], p[9 + 2 * t]));
    }
    acc0 = __builtin_amdgcn_mfma_f32_32x32x16_f16(vf[0], pf0.v, acc0, 0, 0, 0);
    acc0 = __builtin_amdgcn_mfma_f32_32x32x16_f16(vf[1], pf1.v, acc0, 0, 0, 0);
    acc1 = __builtin_amdgcn_mfma_f32_32x32x16_f16(vf[2], pf0.v, acc1, 0, 0, 0);
    acc1 = __builtin_amdgcn_mfma_f32_32x32x16_f16(vf[3], pf1.v, acc1, 0, 0, 0);
  }

  float ltot = lq + __shfl_xor(lq, 32, 64);
  float inv = 1.0f / ltot;
  f16* op = AO + ((size_t)(b * 2048 + irow)) * 1024 + h * 64;
#pragma unroll
  for (int t = 0; t < 4; ++t) {
    int d0 = 8 * t + 4 * hf;
    f16x4 o0, o1;
#pragma unroll
    for (int e = 0; e < 4; ++e) {
      o0[e] = (f16)(acc0[4 * t + e] * inv);
      o1[e] = (f16)(acc1[4 * t + e] * inv);
    }
    *reinterpret_cast<f16x4*>(op + d0) = o0;
    *reinterpret_cast<f16x4*>(op + 32 + d0) = o1;
  }
}

// ---------------- launcher ----------------
extern "C" void kernel_launch(void* const* d_in, const int* in_sizes, int n_in,
                              void* d_out, int out_size, void* d_ws, size_t ws_size,
                              hipStream_t stream) {
  const float* x  = (const float*)d_in[0];
  const float* Wq = (const float*)d_in[1];
  const float* Wk = (const float*)d_in[2];
  const float* Wv = (const float*)d_in[3];
  const float* Wo = (const float*)d_in[4];
  const int* amask = (const int*)d_in[5];
  const int* pE    = (const int*)d_in[6];
  const int* pSkip = (const int*)d_in[7];

  char* ws = (char*)d_ws;
  f16* xb   = (f16*)(ws);                   // x f16; dead after gemm<2> -> AO
  f16* Wqb  = (f16*)(ws + (16u << 20));
  f16* Wkb  = (f16*)(ws + (18u << 20));
  f16* Wvb  = (f16*)(ws + (20u << 20));
  f16* Wob  = (f16*)(ws + (22u << 20));
  f16* Qf   = (f16*)(ws + (24u << 20));
  f16* Kx   = (f16*)(ws + (40u << 20));
  f16* Vx   = (f16*)(ws + (56u << 20));
  float2* sctab = (float2*)(ws + (72u << 20));   // 512 KB
  unsigned* pmask = (unsigned*)(ws + (73u << 20));
  f16* AO   = xb;

  k_misc<<<257, 256, 0, stream>>>(amask, pE, pSkip, sctab, pmask);
  k_cvt<<<4096, 256, 0, stream>>>(x, xb, 8388608);
  k_cvtw<<<2048, 256, 0, stream>>>(Wq, Wk, Wv, Wo, Wqb, Wkb, Wvb, Wob);
  // QKV projections fused with RoPE + fragment-major repack (m-slab XCD map)
  k_gemm<2><<<1536, 256, 0, stream>>>(xb, Wqb, Wkb, Wvb, Qf, Kx, Vx, sctab);
  k_attn<<<4096, 64, 0, stream>>>(Qf, Kx, Vx, pmask, pE, AO);
  // output projection -> fp32 d_out
  k_gemm<1><<<512, 256, 0, stream>>>(AO, Wob, Wob, Wob, d_out, d_out, d_out, nullptr);
}